// Round 7
// baseline (624.977 us; speedup 1.0000x reference)
//
#include <hip/hip_runtime.h>

#define NBINS  20
#define BLOCKS 2048
#define TPB    256
#define NSLOT  32                         // replicated fan-in slots (64 atomics/address)

// ws float layout
#define WS_CNT   0                        // [0,640): 32 slots x 20 count partials
#define WS_W     (NSLOT * NBINS)          // [640,660): final weights
#define WS_ACTR  (WS_W + NBINS)           // [660]: pass-A done counter (int)
#define WS_FIN   (WS_ACTR + 1)            // [661,693): 32 final partial slots
#define WS_BCTR  (WS_FIN + NSLOT)         // [693]: pass-B done counter (int)
#define WS_TOTAL (WS_BCTR + 1)            // 694 floats

__device__ __forceinline__ int bin_of(float t) {
    return min(max((int)(t * 20.0f), 0), NBINS - 1);
}

// ---------- Pass A: counts via wave ballots (targ only), last block -> weights ----------
__global__ __launch_bounds__(TPB, 4)
void dwmse_count(const float* __restrict__ targ, float* __restrict__ ws, int n)
{
    __shared__ float sp[TPB / 64][NBINS];
    __shared__ int   lastf;
    const int tid = threadIdx.x, lane = tid & 63, wv = tid >> 6;

    int cnt[NBINS];
    #pragma unroll
    for (int j = 0; j < NBINS; ++j) cnt[j] = 0;

    const int n4 = n >> 2;
    const float4* t4 = reinterpret_cast<const float4*>(targ);
    const int idx0 = blockIdx.x * TPB + tid;
    const int g    = gridDim.x * TPB;

    if (n4 == g * 8) {
        float4 ta[8];
        #pragma unroll
        for (int u = 0; u < 8; ++u) ta[u] = t4[idx0 + u * g];   // 8 dwordx4 in flight
        #pragma unroll
        for (int u = 0; u < 8; ++u) {
            float te[4] = {ta[u].x, ta[u].y, ta[u].z, ta[u].w};
            #pragma unroll
            for (int e = 0; e < 4; ++e) {
                int b = bin_of(te[e]);
                #pragma unroll
                for (int j = 0; j < NBINS; ++j)
                    cnt[j] += (int)__popcll(__ballot(b == j));  // v_cmp + scalar pipe
            }
        }
    } else {
        for (int i = idx0; i < n4; i += g) {
            float4 t = t4[i];
            float te[4] = {t.x, t.y, t.z, t.w};
            #pragma unroll
            for (int e = 0; e < 4; ++e) {
                int b = bin_of(te[e]);
                #pragma unroll
                for (int j = 0; j < NBINS; ++j)
                    cnt[j] += (int)__popcll(__ballot(b == j));
            }
        }
        for (int k = (n4 << 2) + idx0; k < n; k += g) {
            int b = bin_of(targ[k]);
            #pragma unroll
            for (int j = 0; j < NBINS; ++j)
                cnt[j] += (int)__popcll(__ballot(b == j));
        }
    }

    // cnt[j] is wave-uniform (wave totals). Combine 4 waves, fan into 32 slots.
    if (lane == 0) {
        #pragma unroll
        for (int j = 0; j < NBINS; ++j) sp[wv][j] = (float)cnt[j];
    }
    __syncthreads();
    if (tid < NBINS) {   // wave 0 only
        float c = sp[0][tid] + sp[1][tid] + sp[2][tid] + sp[3][tid];
        unsafeAtomicAdd(&ws[WS_CNT + ((int)blockIdx.x & (NSLOT - 1)) * NBINS + tid], c);
    }
    __threadfence();     // wave 0: drains its own slot-adds before counter bump
    if (tid == 0) {
        int old = atomicAdd(reinterpret_cast<int*>(&ws[WS_ACTR]), 1);
        lastf = (old == (int)gridDim.x - 1);
    }
    __syncthreads();

    if (lastf && tid < 64) {      // last block computes the 20 weights
        float c = 0.0f;
        if (tid < NBINS)
            for (int s = 0; s < NSLOT; ++s)
                c += atomicAdd(&ws[WS_CNT + s * NBINS + tid], 0.0f);  // coherent read

        float w = 0.0f;
        if (tid < NBINS) w = __powf(fmaxf(c, 1.0f), -0.9f);
        float ssum = w;
        #pragma unroll
        for (int off = 32; off; off >>= 1) ssum += __shfl_down(ssum, off);
        ssum = __shfl(ssum, 0);
        float wb = (ssum > 0.0f) ? w * (20.0f / ssum) : w;
        wb = fmaxf(wb, 1.0f);
        if (tid < NBINS) ws[WS_W + tid] = wb;   // visible to pass B via kernel boundary
    }
}

// ---------- Pass B: acc += w[bin(t)] * (p-t)^2 ; last block writes out ----------
__global__ __launch_bounds__(TPB, 4)
void dwmse_wsum(const float* __restrict__ pred, const float* __restrict__ targ,
                float* __restrict__ ws, float* __restrict__ out, int n, float inv_n)
{
    __shared__ float s_w[NBINS];       // 20 words in 20 banks: gather is broadcast, conflict-free
    __shared__ float sp[TPB / 64];
    __shared__ int   lastf;
    const int tid = threadIdx.x, lane = tid & 63, wv = tid >> 6;

    if (tid < NBINS) s_w[tid] = ws[WS_W + tid];
    __syncthreads();

    float acc = 0.0f;
    const int n4 = n >> 2;
    const float4* p4 = reinterpret_cast<const float4*>(pred);
    const float4* t4 = reinterpret_cast<const float4*>(targ);
    const int idx0 = blockIdx.x * TPB + tid;
    const int g    = gridDim.x * TPB;

    if (n4 == g * 8) {
        float4 pa[8], ta[8];
        #pragma unroll
        for (int u = 0; u < 8; ++u) { pa[u] = p4[idx0 + u * g]; ta[u] = t4[idx0 + u * g]; }
        #pragma unroll
        for (int u = 0; u < 8; ++u) {
            float pe[4] = {pa[u].x, pa[u].y, pa[u].z, pa[u].w};
            float te[4] = {ta[u].x, ta[u].y, ta[u].z, ta[u].w};
            #pragma unroll
            for (int e = 0; e < 4; ++e) {
                float d  = pe[e] - te[e];
                float se = d * d;
                acc = fmaf(s_w[bin_of(te[e])], se, acc);
            }
        }
    } else {
        for (int i = idx0; i < n4; i += g) {
            float4 p = p4[i];
            float4 t = t4[i];
            float pe[4] = {p.x, p.y, p.z, p.w};
            float te[4] = {t.x, t.y, t.z, t.w};
            #pragma unroll
            for (int e = 0; e < 4; ++e) {
                float d = pe[e] - te[e];
                acc = fmaf(s_w[bin_of(te[e])], d * d, acc);
            }
        }
        for (int k = (n4 << 2) + idx0; k < n; k += g) {
            float t = targ[k];
            float d = pred[k] - t;
            acc = fmaf(s_w[bin_of(t)], d * d, acc);
        }
    }

    // block reduction
    #pragma unroll
    for (int m = 32; m; m >>= 1) acc += __shfl_xor(acc, m);
    if (lane == 0) sp[wv] = acc;
    __syncthreads();
    if (tid == 0) {
        float v = sp[0] + sp[1] + sp[2] + sp[3];
        unsafeAtomicAdd(&ws[WS_FIN + ((int)blockIdx.x & (NSLOT - 1))], v);
    }
    __threadfence();    // wave 0 drains its add before counter bump
    if (tid == 0) {
        int old = atomicAdd(reinterpret_cast<int*>(&ws[WS_BCTR]), 1);
        lastf = (old == (int)gridDim.x - 1);
    }
    __syncthreads();

    if (lastf && tid < 64) {
        float v = (tid < NSLOT) ? atomicAdd(&ws[WS_FIN + tid], 0.0f) : 0.0f;
        #pragma unroll
        for (int off = 32; off; off >>= 1) v += __shfl_down(v, off);
        if (tid == 0) out[0] = v * inv_n;
    }
}

extern "C" void kernel_launch(void* const* d_in, const int* in_sizes, int n_in,
                              void* d_out, int out_size, void* d_ws, size_t ws_size,
                              hipStream_t stream)
{
    const float* pred = (const float*)d_in[0];
    const float* targ = (const float*)d_in[1];
    float*       out  = (float*)d_out;
    float*       ws   = (float*)d_ws;
    const int n = in_sizes[0];

    hipMemsetAsync(d_ws, 0, WS_TOTAL * sizeof(float), stream);
    dwmse_count<<<BLOCKS, TPB, 0, stream>>>(targ, ws, n);
    dwmse_wsum<<<BLOCKS, TPB, 0, stream>>>(pred, targ, ws, out, n, 1.0f / (float)n);
}